// Round 16
// baseline (160.087 us; speedup 1.0000x reference)
//
#include <hip/hip_runtime.h>
#include <stdint.h>

// D3 dispersion on MI355X (gfx950).
// R15 neutral -> LDS-atomic + libm theories dead. Budget re-fit (harness ws
// poison fill ~45us is inside the timed window): scatter ~43us is the largest
// controllable term; WRITE 56MB invariant across run lengths (8B writes dirty
// 32B sectors, temporally scattered). R16 = R14 + (a) SBLOCKS 128->64 to test
// L2-interference/temporal write-combining, (b) prep kernel takes bcount zero
// + rcovA + rc6pad off scatter's critical path.
// Reference semantics (established R2-R5): fp32 storage; np reference is fp32
// with FTZ in exp -> exceptional one-hot branch iff every masked gaussian
// arg < ln(2^-126) = -87.33654.

typedef unsigned short u16;
#define MAXZ 95
#define NREF 5
#define EXC_CUT -87.33654f
#define NB    1024     // buckets
#define BSH   6        // log2 atoms per bucket
#define BSZ   64       // atoms per bucket
#define CAPSH 12       // bucket capacity 4096 (mean ~1865, sigma ~43)
#define SBLOCKS 64     // scatter blocks: 32768 pairs/block -> 32-rec bucket runs
#define RC_TOTAL (MAXZ * MAXZ * 32)

__device__ __forceinline__ float h2f(u16 h) {
    union { _Float16 h; u16 u; } v; v.u = h; return (float)v.h;
}
__device__ __forceinline__ u16 f2h(float f) {
    union { _Float16 h; u16 u; } v; v.h = (_Float16)f; return v.u;
}

__device__ __forceinline__ float switch_fn(float d) {
    if (d < 10.0f) return 1.0f;
    float x = (12.0f - d) * 0.5f;
    return ((6.0f * x - 15.0f) * x + 10.0f) * x * x * x;
}

__device__ __forceinline__ void calc_weights(const float* __restrict__ rcn_z,
                                             float cni, float* __restrict__ w) {
    float r[NREF], arg[NREF];
    float rmax = -1e30f, marg = -1e30f;
#pragma unroll
    for (int a = 0; a < NREF; a++) {
        r[a] = rcn_z[a];
        rmax = fmaxf(rmax, r[a]);
        float dc = r[a] - cni;
        arg[a] = (-4.0f * dc) * dc;
        if (r[a] >= 0.0f) marg = fmaxf(marg, arg[a]);
    }
    if (marg < EXC_CUT) {
#pragma unroll
        for (int a = 0; a < NREF; a++) w[a] = (r[a] == rmax) ? 1.0f : 0.0f;
    } else {
        float g[NREF], norm = 0.0f;
#pragma unroll
        for (int a = 0; a < NREF; a++) {
            float e = (r[a] >= 0.0f) ? expf(arg[a]) : 0.0f;
            g[a] = e;
            norm += e;
        }
        float inv = 1.0f / fmaxf(norm, 1e-30f);
#pragma unroll
        for (int a = 0; a < NREF; a++) w[a] = g[a] * inv;
    }
}

// ---------------------------------------------------------------------------
// Prep: zero bcount, gather rcovA, repack rc6 -> f16 tiles. Off scatter's
// critical path.
__global__ __launch_bounds__(1024) void prep(const int* __restrict__ Z,
                                             const float* __restrict__ rcov,
                                             const float* __restrict__ rc6,
                                             float* __restrict__ rcovA,
                                             u16* __restrict__ rc6pad,
                                             uint32_t* __restrict__ bcount,
                                             int n_atoms) {
    int g = blockIdx.x * 1024 + (int)threadIdx.x;
    int T = gridDim.x * 1024;
    for (int t = g; t < NB; t += T) bcount[t] = 0;
    for (int i = g; i < n_atoms; i += T) rcovA[i] = rcov[Z[i]];
    for (int id = g; id < RC_TOTAL; id += T) {
        int tile = id >> 5, slot = id & 31;
        rc6pad[id] = (slot < 25) ? f2h(rc6[(size_t)tile * 25 + slot]) : (u16)0;
    }
}

// ---------------------------------------------------------------------------
// Scatter pairs into fixed-stride buckets. Record: {d_fp32, j | il<<16}.
// 4 pairs/thread, vector loads; 64 blocks (long temporal bucket runs).
__global__ __launch_bounds__(1024) void scatter_pairs(const float* __restrict__ dist,
                                                      const int* __restrict__ idx_i,
                                                      const int* __restrict__ idx_j,
                                                      uint32_t* __restrict__ bcount,
                                                      uint2* __restrict__ recs,
                                                      int n_pairs, int chunk) {
    __shared__ uint32_t hist[NB];
    __shared__ uint32_t run[NB];

    for (int t = threadIdx.x; t < NB; t += 1024) hist[t] = 0;
    __syncthreads();
    int lo = blockIdx.x * chunk;
    int hi = min(lo + chunk, n_pairs);

    // pass 1: histogram, 4-wide
    for (int q0 = lo + (int)threadIdx.x * 4; q0 < hi; q0 += 4096) {
        int m = min(4, hi - q0);
        float d4[4];
        int i4[4];
        if (m == 4) {
            float4 dv = *(const float4*)(dist + q0);
            int4 iv = *(const int4*)(idx_i + q0);
            d4[0] = dv.x; d4[1] = dv.y; d4[2] = dv.z; d4[3] = dv.w;
            i4[0] = iv.x; i4[1] = iv.y; i4[2] = iv.z; i4[3] = iv.w;
        } else {
            for (int s = 0; s < m; s++) { d4[s] = dist[q0 + s]; i4[s] = idx_i[q0 + s]; }
        }
#pragma unroll
        for (int s = 0; s < 4; s++) {
            if (s < m && d4[s] < 12.0f)
                atomicAdd(&hist[((uint32_t)i4[s]) >> BSH], 1u);
        }
    }
    __syncthreads();
    for (int t = threadIdx.x; t < NB; t += 1024) {
        uint32_t h = hist[t];
        run[t] = h ? atomicAdd(&bcount[t], h) : 0u;
    }
    __syncthreads();

    // pass 2: scatter, 4-wide
    for (int q0 = lo + (int)threadIdx.x * 4; q0 < hi; q0 += 4096) {
        int m = min(4, hi - q0);
        float d4[4];
        int i4[4], j4[4];
        if (m == 4) {
            float4 dv = *(const float4*)(dist + q0);
            int4 iv = *(const int4*)(idx_i + q0);
            int4 jv = *(const int4*)(idx_j + q0);
            d4[0] = dv.x; d4[1] = dv.y; d4[2] = dv.z; d4[3] = dv.w;
            i4[0] = iv.x; i4[1] = iv.y; i4[2] = iv.z; i4[3] = iv.w;
            j4[0] = jv.x; j4[1] = jv.y; j4[2] = jv.z; j4[3] = jv.w;
        } else {
            for (int s = 0; s < m; s++) {
                d4[s] = dist[q0 + s]; i4[s] = idx_i[q0 + s]; j4[s] = idx_j[q0 + s];
            }
        }
#pragma unroll
        for (int s = 0; s < 4; s++) {
            if (s >= m) continue;
            float d = d4[s];
            if (d >= 12.0f) continue;              // sw == 0: drop
            uint32_t i = (uint32_t)i4[s];
            uint32_t b = i >> BSH;
            uint32_t pos = atomicAdd(&run[b], 1u);
            if (pos < (1u << CAPSH)) {
                uint32_t packed = ((uint32_t)j4[s] & 0xFFFFu) |
                                  ((i & (BSZ - 1u)) << 16);
                recs[((size_t)b << CAPSH) + pos] = make_uint2(__float_as_uint(d), packed);
            }
        }
    }
}

// ---------------------------------------------------------------------------
// CN + fused weights: one block per bucket, depth-3 rolling pipeline (R14).
__global__ __launch_bounds__(256) void cn_weights_bucket(const uint2* __restrict__ recs,
                                                         const uint32_t* __restrict__ bcount,
                                                         const float* __restrict__ rcovA,
                                                         const int* __restrict__ Z,
                                                         const float* __restrict__ rcn,
                                                         const float* __restrict__ r2r4,
                                                         uint4* __restrict__ arec_h,
                                                         int n_atoms) {
    __shared__ float lrc[BSZ];
    __shared__ float acc[BSZ];
    int b = blockIdx.x;
    int base = b << BSH;
    if (threadIdx.x < BSZ) {
        int i = base + (int)threadIdx.x;
        lrc[threadIdx.x] = (i < n_atoms) ? rcovA[i] : 0.0f;
        acc[threadIdx.x] = 0.0f;
    }
    __syncthreads();
    uint32_t n = min(bcount[b], 1u << CAPSH);
    const uint2* r0 = recs + ((size_t)b << CAPSH);
    if (n) {
        uint32_t nm1 = n - 1;
        uint32_t k = threadIdx.x;
        uint2 recA = r0[min(k, nm1)];
        uint2 recB = r0[min(k + 256, nm1)];
        float rjA = rcovA[recA.y & 0xFFFF];
        for (; k < n; k += 256) {
            uint2 recC = r0[min(k + 512, nm1)];
            float rjB = rcovA[recB.y & 0xFFFF];
            float d = __uint_as_float(recA.x);
            int il = (recA.y >> 16) & (BSZ - 1);
            float rij = lrc[il] + rjA;
            float sw = switch_fn(d);
            atomicAdd(&acc[il], sw / (1.0f + expf(-16.0f * (rij / d - 1.0f))));
            recA = recB; recB = recC; rjA = rjB;
        }
    }
    __syncthreads();
    if (threadIdx.x < BSZ) {
        int i = base + (int)threadIdx.x;
        if (i < n_atoms) {
            int z = Z[i];
            float w[NREF];
            calc_weights(rcn + (size_t)z * NREF, acc[threadIdx.x], w);
            uint4 pk;
            pk.x = (uint32_t)f2h(w[0]) | ((uint32_t)f2h(w[1]) << 16);
            pk.y = (uint32_t)f2h(w[2]) | ((uint32_t)f2h(w[3]) << 16);
            pk.z = (uint32_t)f2h(w[4]) | ((uint32_t)f2h(r2r4[z]) << 16);
            pk.w = (uint32_t)z;
            arec_h[i] = pk;
        }
    }
}

// ---------------------------------------------------------------------------
// Energy: one block per bucket, depth-3 rolling pipeline (R14).
__global__ __launch_bounds__(256) void energy_bucket(const uint2* __restrict__ recs,
                                                     const uint32_t* __restrict__ bcount,
                                                     const uint4* __restrict__ arec_h,
                                                     const u16* __restrict__ rc6pad,
                                                     const float* __restrict__ s6p,
                                                     const float* __restrict__ s8p,
                                                     const float* __restrict__ a1p,
                                                     const float* __restrict__ a2p,
                                                     float* __restrict__ eout,
                                                     int n_atoms) {
    __shared__ float4 la0[BSZ];
    __shared__ float4 la1[BSZ];
    __shared__ float  acc[BSZ];
    int b = blockIdx.x;
    int base = b << BSH;
    if (threadIdx.x < BSZ) {
        int i = min(base + (int)threadIdx.x, n_atoms - 1);
        uint4 pk = arec_h[i];
        la0[threadIdx.x] = make_float4(h2f(pk.x & 0xFFFFu), h2f(pk.x >> 16),
                                       h2f(pk.y & 0xFFFFu), h2f(pk.y >> 16));
        la1[threadIdx.x] = make_float4(h2f(pk.z & 0xFFFFu), h2f(pk.z >> 16),
                                       __int_as_float((int)pk.w), 0.0f);
        acc[threadIdx.x] = 0.0f;
    }
    __syncthreads();
    float s6 = s6p[0], s8 = s8p[0], a1 = a1p[0], a2 = a2p[0];
    uint32_t n = min(bcount[b], 1u << CAPSH);
    const uint2* r0 = recs + ((size_t)b << CAPSH);
    if (n) {
        uint32_t nm1 = n - 1;
        uint32_t k = threadIdx.x;
        uint2 recA = r0[min(k, nm1)];
        uint2 recB = r0[min(k + 256, nm1)];
        uint4 pjA = arec_h[recA.y & 0xFFFFu];
        for (; k < n; k += 256) {
            uint2 recC = r0[min(k + 512, nm1)];
            uint4 pjB = arec_h[recB.y & 0xFFFFu];

            int il = (recA.y >> 16) & (BSZ - 1);
            float4 ai1 = la1[il];
            int zi = __float_as_int(ai1.z);
            int zj = (int)pjA.w;
            const uint4* T4 = (const uint4*)(rc6pad + (size_t)(zi * MAXZ + zj) * 32);
            uint4 t0 = T4[0], t1 = T4[1], t2 = T4[2];
            uint32_t t3 = ((const uint32_t*)T4)[12];

            float d = __uint_as_float(recA.x);
            float4 ai0 = la0[il];
            float wi[NREF] = {ai0.x, ai0.y, ai0.z, ai0.w, ai1.x};
            float wj[NREF] = {h2f(pjA.x & 0xFFFFu), h2f(pjA.x >> 16),
                              h2f(pjA.y & 0xFFFFu), h2f(pjA.y >> 16),
                              h2f(pjA.z & 0xFFFFu)};
            float r2r4j = h2f(pjA.z >> 16);

            float tt[25];
            uint32_t tw[12] = {t0.x, t0.y, t0.z, t0.w, t1.x, t1.y, t1.z, t1.w,
                               t2.x, t2.y, t2.z, t2.w};
#pragma unroll
            for (int k2 = 0; k2 < 12; k2++) {
                tt[2 * k2]     = h2f((u16)(tw[k2] & 0xFFFFu));
                tt[2 * k2 + 1] = h2f((u16)(tw[k2] >> 16));
            }
            tt[24] = h2f((u16)(t3 & 0xFFFFu));

            float c6 = 0.0f;
#pragma unroll
            for (int a = 0; a < NREF; a++) {
                float ss = 0.0f;
#pragma unroll
                for (int bb = 0; bb < NREF; bb++) ss = fmaf(wj[bb], tt[a * NREF + bb], ss);
                c6 = fmaf(wi[a], ss, c6);
            }

            float qq = 3.0f * ai1.y * r2r4j;
            float rr = a1 * sqrtf(qq) + a2;
            float d2 = d * d;
            float d6 = d2 * d2 * d2;
            float d8 = d6 * d2;
            float rr2 = rr * rr;
            float rr6 = rr2 * rr2 * rr2;
            float rr8 = rr6 * rr2;
            float sw = switch_fn(d);

            float e = -0.5f * (s6 * c6 / (d6 + rr6) + s8 * qq * c6 / (d8 + rr8)) * sw;
            atomicAdd(&acc[il], e);

            recA = recB; recB = recC; pjA = pjB;
        }
    }
    __syncthreads();
    if (threadIdx.x < BSZ) {
        int i = base + (int)threadIdx.x;
        if (i < n_atoms) eout[i] = acc[threadIdx.x];
    }
}

// ---------------------------------------------------------------------------
// Slim fallback (small workspace): R5-style global-atomic fp32 path.
__global__ __launch_bounds__(256) void pair_cn_slim(const float* __restrict__ dist,
                                                    const float* __restrict__ rcov,
                                                    const int* __restrict__ Z,
                                                    const int* __restrict__ idx_i,
                                                    const int* __restrict__ idx_j,
                                                    float* __restrict__ cn,
                                                    int n_pairs) {
    int p = blockIdx.x * blockDim.x + threadIdx.x;
    if (p >= n_pairs) return;
    float d = dist[p];
    if (d >= 12.0f) return;
    float rij = rcov[Z[idx_i[p]]] + rcov[Z[idx_j[p]]];
    float sw = switch_fn(d);
    atomicAdd(&cn[idx_i[p]], sw / (1.0f + expf(-16.0f * (rij / d - 1.0f))));
}

__global__ __launch_bounds__(256) void pair_energy_slim(const float* __restrict__ dist,
                                                        const int* __restrict__ Z,
                                                        const int* __restrict__ idx_i,
                                                        const int* __restrict__ idx_j,
                                                        const float* __restrict__ cn,
                                                        const float* __restrict__ rcn,
                                                        const float* __restrict__ r2r4,
                                                        const float* __restrict__ rc6,
                                                        const float* __restrict__ s6p,
                                                        const float* __restrict__ s8p,
                                                        const float* __restrict__ a1p,
                                                        const float* __restrict__ a2p,
                                                        float* __restrict__ eout,
                                                        int n_pairs) {
    int p = blockIdx.x * blockDim.x + threadIdx.x;
    if (p >= n_pairs) return;
    float d = dist[p];
    if (d >= 12.0f) return;
    int i = idx_i[p], j = idx_j[p];
    int zi = Z[i], zj = Z[j];
    float wi[NREF], wj[NREF];
    calc_weights(rcn + (size_t)zi * NREF, cn[i], wi);
    calc_weights(rcn + (size_t)zj * NREF, cn[j], wj);
    const float* T = rc6 + (size_t)(zi * MAXZ + zj) * 25;
    float c6 = 0.0f;
#pragma unroll
    for (int a = 0; a < NREF; a++) {
        float s = 0.0f;
#pragma unroll
        for (int bb = 0; bb < NREF; bb++) s = fmaf(wj[bb], T[a * NREF + bb], s);
        c6 = fmaf(wi[a], s, c6);
    }
    float qq = 3.0f * r2r4[zi] * r2r4[zj];
    float rr = a1p[0] * sqrtf(qq) + a2p[0];
    float d2 = d * d;
    float d6 = d2 * d2 * d2;
    float d8 = d6 * d2;
    float rr2 = rr * rr;
    float rr6 = rr2 * rr2 * rr2;
    float rr8 = rr6 * rr2;
    float sw = switch_fn(d);
    float e = -0.5f * (s6p[0] * c6 / (d6 + rr6) + s8p[0] * qq * c6 / (d8 + rr8)) * sw;
    atomicAdd(&eout[i], e);
}

// ---------------------------------------------------------------------------
extern "C" void kernel_launch(void* const* d_in, const int* in_sizes, int n_in,
                              void* d_out, int out_size, void* d_ws, size_t ws_size,
                              hipStream_t stream) {
    const float* dist = (const float*)d_in[0];
    const float* rcov = (const float*)d_in[1];
    const float* rcn  = (const float*)d_in[2];
    const float* rc6  = (const float*)d_in[3];
    const float* r2r4 = (const float*)d_in[4];
    const float* s6p  = (const float*)d_in[5];
    const float* s8p  = (const float*)d_in[6];
    const float* a1p  = (const float*)d_in[7];
    const float* a2p  = (const float*)d_in[8];
    const int* Z    = (const int*)d_in[9];
    const int* idxi = (const int*)d_in[10];
    const int* idxj = (const int*)d_in[11];
    float* out = (float*)d_out;

    int n_pairs = in_sizes[0];
    int n_atoms = in_sizes[9];

    char* ws = (char*)d_ws;
    size_t o_bcount = 0;                                       // NB u32 (pad 4K)
    size_t o_rcovA  = 4096;
    size_t o_arec   = (o_rcovA + (size_t)n_atoms * 4 + 15) & ~(size_t)15;
    size_t o_rc6    = (o_arec + (size_t)n_atoms * 16 + 63) & ~(size_t)63;
    size_t o_recs   = (o_rc6 + (size_t)RC_TOTAL * 2 + 255) & ~(size_t)255;
    size_t need     = o_recs + ((size_t)NB << CAPSH) * 8;

    uint32_t* bcount = (uint32_t*)(ws + o_bcount);
    float* rcovA  = (float*)(ws + o_rcovA);
    uint4* arec_h = (uint4*)(ws + o_arec);
    u16*   rcpad  = (u16*)(ws + o_rc6);
    uint2* recs   = (uint2*)(ws + o_recs);

    if (ws_size >= need && n_atoms <= NB * BSZ && n_atoms <= 65536) {
        prep<<<64, 1024, 0, stream>>>(Z, rcov, rc6, rcovA, rcpad, bcount, n_atoms);
        int chunk = (n_pairs + SBLOCKS - 1) / SBLOCKS;
        scatter_pairs<<<SBLOCKS, 1024, 0, stream>>>(dist, idxi, idxj,
                                                    bcount, recs, n_pairs, chunk);
        cn_weights_bucket<<<NB, 256, 0, stream>>>(recs, bcount, rcovA, Z, rcn, r2r4,
                                                  arec_h, n_atoms);
        energy_bucket<<<NB, 256, 0, stream>>>(recs, bcount, arec_h, rcpad,
                                              s6p, s8p, a1p, a2p, out, n_atoms);
    } else {
        int pgrid = (n_pairs + 255) / 256;
        float* cn = (float*)(ws + o_rcovA);      // reuse slot as cn accumulator
        hipMemsetAsync(out, 0, (size_t)n_atoms * 4, stream);
        hipMemsetAsync(cn, 0, (size_t)n_atoms * 4, stream);
        pair_cn_slim<<<pgrid, 256, 0, stream>>>(dist, rcov, Z, idxi, idxj, cn, n_pairs);
        pair_energy_slim<<<pgrid, 256, 0, stream>>>(dist, Z, idxi, idxj, cn, rcn, r2r4,
                                                    rc6, s6p, s8p, a1p, a2p, out, n_pairs);
    }
}

// Round 17
// 144.467 us; speedup vs baseline: 1.1081x; 1.1081x over previous
//
#include <hip/hip_runtime.h>
#include <stdint.h>

// D3 dispersion on MI355X (gfx950). FINAL (R17 = R14, the empirical optimum).
// Pipeline: scatter (128x1024, 4-wide vectorized, prologue fills rcovA+f16
// rc6pad) -> cn+weights per 64-atom bucket (LDS accum, fused weight pack)
// -> energy per bucket (f16 16B arec gather + 64B tile gather, LDS accum).
// Zero global fp32 atomics. 147us total, of which ~45us is the harness's
// 268MB ws-poison fill at 75% HBM peak (untouchable).
// Theory ledger (all falsified for the residual): wave count (R9), coop
// fusion (R7), per-thread batching (R11), record packing (R13), SW pipe
// (R14 neutral), LDS sub-slots/fast-math (R15), scatter run-length (R16:
// write-combining real but parallelism-limited at <128 blocks).
// Reference semantics (established R2-R5): fp32 storage; np reference is fp32
// with FTZ in exp -> exceptional one-hot branch iff every masked gaussian
// arg < ln(2^-126) = -87.33654.

typedef unsigned short u16;
#define MAXZ 95
#define NREF 5
#define EXC_CUT -87.33654f
#define NB    1024     // buckets
#define BSH   6        // log2 atoms per bucket
#define BSZ   64       // atoms per bucket
#define CAPSH 12       // bucket capacity 4096 (mean ~1865, sigma ~43)
#define SBLOCKS 128    // scatter blocks (proven optimum: R8=256/R16=64 worse)
#define RC_TOTAL (MAXZ * MAXZ * 32)

__device__ __forceinline__ float h2f(u16 h) {
    union { _Float16 h; u16 u; } v; v.u = h; return (float)v.h;
}
__device__ __forceinline__ u16 f2h(float f) {
    union { _Float16 h; u16 u; } v; v.h = (_Float16)f; return v.u;
}

__device__ __forceinline__ float switch_fn(float d) {
    if (d < 10.0f) return 1.0f;
    float x = (12.0f - d) * 0.5f;
    return ((6.0f * x - 15.0f) * x + 10.0f) * x * x * x;
}

__device__ __forceinline__ void calc_weights(const float* __restrict__ rcn_z,
                                             float cni, float* __restrict__ w) {
    float r[NREF], arg[NREF];
    float rmax = -1e30f, marg = -1e30f;
#pragma unroll
    for (int a = 0; a < NREF; a++) {
        r[a] = rcn_z[a];
        rmax = fmaxf(rmax, r[a]);
        float dc = r[a] - cni;
        arg[a] = (-4.0f * dc) * dc;
        if (r[a] >= 0.0f) marg = fmaxf(marg, arg[a]);
    }
    if (marg < EXC_CUT) {
#pragma unroll
        for (int a = 0; a < NREF; a++) w[a] = (r[a] == rmax) ? 1.0f : 0.0f;
    } else {
        float g[NREF], norm = 0.0f;
#pragma unroll
        for (int a = 0; a < NREF; a++) {
            float e = (r[a] >= 0.0f) ? expf(arg[a]) : 0.0f;
            g[a] = e;
            norm += e;
        }
        float inv = 1.0f / fmaxf(norm, 1e-30f);
#pragma unroll
        for (int a = 0; a < NREF; a++) w[a] = g[a] * inv;
    }
}

// ---------------------------------------------------------------------------
// Scatter pairs into fixed-stride buckets; prologue fills rcovA + f16 rc6pad.
// Record: {d_fp32, j | il<<16}. 4 pairs/thread, vector loads.
__global__ __launch_bounds__(1024) void scatter_pairs(const float* __restrict__ dist,
                                                      const int* __restrict__ idx_i,
                                                      const int* __restrict__ idx_j,
                                                      const int* __restrict__ Z,
                                                      const float* __restrict__ rcov,
                                                      const float* __restrict__ rc6,
                                                      float* __restrict__ rcovA,
                                                      u16* __restrict__ rc6pad,
                                                      uint32_t* __restrict__ bcount,
                                                      uint2* __restrict__ recs,
                                                      int n_pairs, int n_atoms,
                                                      int chunk) {
    __shared__ uint32_t hist[NB];
    __shared__ uint32_t run[NB];

    int g = blockIdx.x * 1024 + (int)threadIdx.x;
    int T = gridDim.x * 1024;
    for (int i = g; i < n_atoms; i += T) rcovA[i] = rcov[Z[i]];
    for (int id = g; id < RC_TOTAL; id += T) {
        int tile = id >> 5, slot = id & 31;
        rc6pad[id] = (slot < 25) ? f2h(rc6[(size_t)tile * 25 + slot]) : (u16)0;
    }

    for (int t = threadIdx.x; t < NB; t += 1024) hist[t] = 0;
    __syncthreads();
    int lo = blockIdx.x * chunk;
    int hi = min(lo + chunk, n_pairs);

    // pass 1: histogram, 4-wide
    for (int q0 = lo + (int)threadIdx.x * 4; q0 < hi; q0 += 4096) {
        int m = min(4, hi - q0);
        float d4[4];
        int i4[4];
        if (m == 4) {
            float4 dv = *(const float4*)(dist + q0);
            int4 iv = *(const int4*)(idx_i + q0);
            d4[0] = dv.x; d4[1] = dv.y; d4[2] = dv.z; d4[3] = dv.w;
            i4[0] = iv.x; i4[1] = iv.y; i4[2] = iv.z; i4[3] = iv.w;
        } else {
            for (int s = 0; s < m; s++) { d4[s] = dist[q0 + s]; i4[s] = idx_i[q0 + s]; }
        }
#pragma unroll
        for (int s = 0; s < 4; s++) {
            if (s < m && d4[s] < 12.0f)
                atomicAdd(&hist[((uint32_t)i4[s]) >> BSH], 1u);
        }
    }
    __syncthreads();
    for (int t = threadIdx.x; t < NB; t += 1024) {
        uint32_t h = hist[t];
        run[t] = h ? atomicAdd(&bcount[t], h) : 0u;
    }
    __syncthreads();

    // pass 2: scatter, 4-wide
    for (int q0 = lo + (int)threadIdx.x * 4; q0 < hi; q0 += 4096) {
        int m = min(4, hi - q0);
        float d4[4];
        int i4[4], j4[4];
        if (m == 4) {
            float4 dv = *(const float4*)(dist + q0);
            int4 iv = *(const int4*)(idx_i + q0);
            int4 jv = *(const int4*)(idx_j + q0);
            d4[0] = dv.x; d4[1] = dv.y; d4[2] = dv.z; d4[3] = dv.w;
            i4[0] = iv.x; i4[1] = iv.y; i4[2] = iv.z; i4[3] = iv.w;
            j4[0] = jv.x; j4[1] = jv.y; j4[2] = jv.z; j4[3] = jv.w;
        } else {
            for (int s = 0; s < m; s++) {
                d4[s] = dist[q0 + s]; i4[s] = idx_i[q0 + s]; j4[s] = idx_j[q0 + s];
            }
        }
#pragma unroll
        for (int s = 0; s < 4; s++) {
            if (s >= m) continue;
            float d = d4[s];
            if (d >= 12.0f) continue;              // sw == 0: drop
            uint32_t i = (uint32_t)i4[s];
            uint32_t b = i >> BSH;
            uint32_t pos = atomicAdd(&run[b], 1u);
            if (pos < (1u << CAPSH)) {
                uint32_t packed = ((uint32_t)j4[s] & 0xFFFFu) |
                                  ((i & (BSZ - 1u)) << 16);
                recs[((size_t)b << CAPSH) + pos] = make_uint2(__float_as_uint(d), packed);
            }
        }
    }
}

// ---------------------------------------------------------------------------
// CN + fused weights: one block per bucket, depth-3 rolling pipeline.
__global__ __launch_bounds__(256) void cn_weights_bucket(const uint2* __restrict__ recs,
                                                         const uint32_t* __restrict__ bcount,
                                                         const float* __restrict__ rcovA,
                                                         const int* __restrict__ Z,
                                                         const float* __restrict__ rcn,
                                                         const float* __restrict__ r2r4,
                                                         uint4* __restrict__ arec_h,
                                                         int n_atoms) {
    __shared__ float lrc[BSZ];
    __shared__ float acc[BSZ];
    int b = blockIdx.x;
    int base = b << BSH;
    if (threadIdx.x < BSZ) {
        int i = base + (int)threadIdx.x;
        lrc[threadIdx.x] = (i < n_atoms) ? rcovA[i] : 0.0f;
        acc[threadIdx.x] = 0.0f;
    }
    __syncthreads();
    uint32_t n = min(bcount[b], 1u << CAPSH);
    const uint2* r0 = recs + ((size_t)b << CAPSH);
    if (n) {
        uint32_t nm1 = n - 1;
        uint32_t k = threadIdx.x;
        uint2 recA = r0[min(k, nm1)];
        uint2 recB = r0[min(k + 256, nm1)];
        float rjA = rcovA[recA.y & 0xFFFF];
        for (; k < n; k += 256) {
            uint2 recC = r0[min(k + 512, nm1)];
            float rjB = rcovA[recB.y & 0xFFFF];
            float d = __uint_as_float(recA.x);
            int il = (recA.y >> 16) & (BSZ - 1);
            float rij = lrc[il] + rjA;
            float sw = switch_fn(d);
            atomicAdd(&acc[il], sw / (1.0f + expf(-16.0f * (rij / d - 1.0f))));
            recA = recB; recB = recC; rjA = rjB;
        }
    }
    __syncthreads();
    if (threadIdx.x < BSZ) {
        int i = base + (int)threadIdx.x;
        if (i < n_atoms) {
            int z = Z[i];
            float w[NREF];
            calc_weights(rcn + (size_t)z * NREF, acc[threadIdx.x], w);
            uint4 pk;
            pk.x = (uint32_t)f2h(w[0]) | ((uint32_t)f2h(w[1]) << 16);
            pk.y = (uint32_t)f2h(w[2]) | ((uint32_t)f2h(w[3]) << 16);
            pk.z = (uint32_t)f2h(w[4]) | ((uint32_t)f2h(r2r4[z]) << 16);
            pk.w = (uint32_t)z;
            arec_h[i] = pk;
        }
    }
}

// ---------------------------------------------------------------------------
// Energy: one block per bucket, depth-3 rolling pipeline.
__global__ __launch_bounds__(256) void energy_bucket(const uint2* __restrict__ recs,
                                                     const uint32_t* __restrict__ bcount,
                                                     const uint4* __restrict__ arec_h,
                                                     const u16* __restrict__ rc6pad,
                                                     const float* __restrict__ s6p,
                                                     const float* __restrict__ s8p,
                                                     const float* __restrict__ a1p,
                                                     const float* __restrict__ a2p,
                                                     float* __restrict__ eout,
                                                     int n_atoms) {
    __shared__ float4 la0[BSZ];
    __shared__ float4 la1[BSZ];
    __shared__ float  acc[BSZ];
    int b = blockIdx.x;
    int base = b << BSH;
    if (threadIdx.x < BSZ) {
        int i = min(base + (int)threadIdx.x, n_atoms - 1);
        uint4 pk = arec_h[i];
        la0[threadIdx.x] = make_float4(h2f(pk.x & 0xFFFFu), h2f(pk.x >> 16),
                                       h2f(pk.y & 0xFFFFu), h2f(pk.y >> 16));
        la1[threadIdx.x] = make_float4(h2f(pk.z & 0xFFFFu), h2f(pk.z >> 16),
                                       __int_as_float((int)pk.w), 0.0f);
        acc[threadIdx.x] = 0.0f;
    }
    __syncthreads();
    float s6 = s6p[0], s8 = s8p[0], a1 = a1p[0], a2 = a2p[0];
    uint32_t n = min(bcount[b], 1u << CAPSH);
    const uint2* r0 = recs + ((size_t)b << CAPSH);
    if (n) {
        uint32_t nm1 = n - 1;
        uint32_t k = threadIdx.x;
        uint2 recA = r0[min(k, nm1)];
        uint2 recB = r0[min(k + 256, nm1)];
        uint4 pjA = arec_h[recA.y & 0xFFFFu];
        for (; k < n; k += 256) {
            uint2 recC = r0[min(k + 512, nm1)];
            uint4 pjB = arec_h[recB.y & 0xFFFFu];

            int il = (recA.y >> 16) & (BSZ - 1);
            float4 ai1 = la1[il];
            int zi = __float_as_int(ai1.z);
            int zj = (int)pjA.w;
            const uint4* T4 = (const uint4*)(rc6pad + (size_t)(zi * MAXZ + zj) * 32);
            uint4 t0 = T4[0], t1 = T4[1], t2 = T4[2];
            uint32_t t3 = ((const uint32_t*)T4)[12];

            float d = __uint_as_float(recA.x);
            float4 ai0 = la0[il];
            float wi[NREF] = {ai0.x, ai0.y, ai0.z, ai0.w, ai1.x};
            float wj[NREF] = {h2f(pjA.x & 0xFFFFu), h2f(pjA.x >> 16),
                              h2f(pjA.y & 0xFFFFu), h2f(pjA.y >> 16),
                              h2f(pjA.z & 0xFFFFu)};
            float r2r4j = h2f(pjA.z >> 16);

            float tt[25];
            uint32_t tw[12] = {t0.x, t0.y, t0.z, t0.w, t1.x, t1.y, t1.z, t1.w,
                               t2.x, t2.y, t2.z, t2.w};
#pragma unroll
            for (int k2 = 0; k2 < 12; k2++) {
                tt[2 * k2]     = h2f((u16)(tw[k2] & 0xFFFFu));
                tt[2 * k2 + 1] = h2f((u16)(tw[k2] >> 16));
            }
            tt[24] = h2f((u16)(t3 & 0xFFFFu));

            float c6 = 0.0f;
#pragma unroll
            for (int a = 0; a < NREF; a++) {
                float ss = 0.0f;
#pragma unroll
                for (int bb = 0; bb < NREF; bb++) ss = fmaf(wj[bb], tt[a * NREF + bb], ss);
                c6 = fmaf(wi[a], ss, c6);
            }

            float qq = 3.0f * ai1.y * r2r4j;
            float rr = a1 * sqrtf(qq) + a2;
            float d2 = d * d;
            float d6 = d2 * d2 * d2;
            float d8 = d6 * d2;
            float rr2 = rr * rr;
            float rr6 = rr2 * rr2 * rr2;
            float rr8 = rr6 * rr2;
            float sw = switch_fn(d);

            float e = -0.5f * (s6 * c6 / (d6 + rr6) + s8 * qq * c6 / (d8 + rr8)) * sw;
            atomicAdd(&acc[il], e);

            recA = recB; recB = recC; pjA = pjB;
        }
    }
    __syncthreads();
    if (threadIdx.x < BSZ) {
        int i = base + (int)threadIdx.x;
        if (i < n_atoms) eout[i] = acc[threadIdx.x];
    }
}

// ---------------------------------------------------------------------------
// Slim fallback (small workspace): R5-style global-atomic fp32 path.
__global__ __launch_bounds__(256) void pair_cn_slim(const float* __restrict__ dist,
                                                    const float* __restrict__ rcov,
                                                    const int* __restrict__ Z,
                                                    const int* __restrict__ idx_i,
                                                    const int* __restrict__ idx_j,
                                                    float* __restrict__ cn,
                                                    int n_pairs) {
    int p = blockIdx.x * blockDim.x + threadIdx.x;
    if (p >= n_pairs) return;
    float d = dist[p];
    if (d >= 12.0f) return;
    float rij = rcov[Z[idx_i[p]]] + rcov[Z[idx_j[p]]];
    float sw = switch_fn(d);
    atomicAdd(&cn[idx_i[p]], sw / (1.0f + expf(-16.0f * (rij / d - 1.0f))));
}

__global__ __launch_bounds__(256) void pair_energy_slim(const float* __restrict__ dist,
                                                        const int* __restrict__ Z,
                                                        const int* __restrict__ idx_i,
                                                        const int* __restrict__ idx_j,
                                                        const float* __restrict__ cn,
                                                        const float* __restrict__ rcn,
                                                        const float* __restrict__ r2r4,
                                                        const float* __restrict__ rc6,
                                                        const float* __restrict__ s6p,
                                                        const float* __restrict__ s8p,
                                                        const float* __restrict__ a1p,
                                                        const float* __restrict__ a2p,
                                                        float* __restrict__ eout,
                                                        int n_pairs) {
    int p = blockIdx.x * blockDim.x + threadIdx.x;
    if (p >= n_pairs) return;
    float d = dist[p];
    if (d >= 12.0f) return;
    int i = idx_i[p], j = idx_j[p];
    int zi = Z[i], zj = Z[j];
    float wi[NREF], wj[NREF];
    calc_weights(rcn + (size_t)zi * NREF, cn[i], wi);
    calc_weights(rcn + (size_t)zj * NREF, cn[j], wj);
    const float* T = rc6 + (size_t)(zi * MAXZ + zj) * 25;
    float c6 = 0.0f;
#pragma unroll
    for (int a = 0; a < NREF; a++) {
        float s = 0.0f;
#pragma unroll
        for (int bb = 0; bb < NREF; bb++) s = fmaf(wj[bb], T[a * NREF + bb], s);
        c6 = fmaf(wi[a], s, c6);
    }
    float qq = 3.0f * r2r4[zi] * r2r4[zj];
    float rr = a1p[0] * sqrtf(qq) + a2p[0];
    float d2 = d * d;
    float d6 = d2 * d2 * d2;
    float d8 = d6 * d2;
    float rr2 = rr * rr;
    float rr6 = rr2 * rr2 * rr2;
    float rr8 = rr6 * rr2;
    float sw = switch_fn(d);
    float e = -0.5f * (s6p[0] * c6 / (d6 + rr6) + s8p[0] * qq * c6 / (d8 + rr8)) * sw;
    atomicAdd(&eout[i], e);
}

// ---------------------------------------------------------------------------
extern "C" void kernel_launch(void* const* d_in, const int* in_sizes, int n_in,
                              void* d_out, int out_size, void* d_ws, size_t ws_size,
                              hipStream_t stream) {
    const float* dist = (const float*)d_in[0];
    const float* rcov = (const float*)d_in[1];
    const float* rcn  = (const float*)d_in[2];
    const float* rc6  = (const float*)d_in[3];
    const float* r2r4 = (const float*)d_in[4];
    const float* s6p  = (const float*)d_in[5];
    const float* s8p  = (const float*)d_in[6];
    const float* a1p  = (const float*)d_in[7];
    const float* a2p  = (const float*)d_in[8];
    const int* Z    = (const int*)d_in[9];
    const int* idxi = (const int*)d_in[10];
    const int* idxj = (const int*)d_in[11];
    float* out = (float*)d_out;

    int n_pairs = in_sizes[0];
    int n_atoms = in_sizes[9];

    char* ws = (char*)d_ws;
    size_t o_bcount = 0;                                       // NB u32 (pad 4K)
    size_t o_rcovA  = 4096;
    size_t o_arec   = (o_rcovA + (size_t)n_atoms * 4 + 15) & ~(size_t)15;
    size_t o_rc6    = (o_arec + (size_t)n_atoms * 16 + 63) & ~(size_t)63;
    size_t o_recs   = (o_rc6 + (size_t)RC_TOTAL * 2 + 255) & ~(size_t)255;
    size_t need     = o_recs + ((size_t)NB << CAPSH) * 8;

    uint32_t* bcount = (uint32_t*)(ws + o_bcount);
    float* rcovA  = (float*)(ws + o_rcovA);
    uint4* arec_h = (uint4*)(ws + o_arec);
    u16*   rcpad  = (u16*)(ws + o_rc6);
    uint2* recs   = (uint2*)(ws + o_recs);

    if (ws_size >= need && n_atoms <= NB * BSZ && n_atoms <= 65536) {
        hipMemsetAsync(bcount, 0, NB * 4, stream);
        int chunk = (n_pairs + SBLOCKS - 1) / SBLOCKS;
        scatter_pairs<<<SBLOCKS, 1024, 0, stream>>>(dist, idxi, idxj, Z, rcov, rc6,
                                                    rcovA, rcpad, bcount, recs,
                                                    n_pairs, n_atoms, chunk);
        cn_weights_bucket<<<NB, 256, 0, stream>>>(recs, bcount, rcovA, Z, rcn, r2r4,
                                                  arec_h, n_atoms);
        energy_bucket<<<NB, 256, 0, stream>>>(recs, bcount, arec_h, rcpad,
                                              s6p, s8p, a1p, a2p, out, n_atoms);
    } else {
        int pgrid = (n_pairs + 255) / 256;
        float* cn = (float*)(ws + o_rcovA);      // reuse slot as cn accumulator
        hipMemsetAsync(out, 0, (size_t)n_atoms * 4, stream);
        hipMemsetAsync(cn, 0, (size_t)n_atoms * 4, stream);
        pair_cn_slim<<<pgrid, 256, 0, stream>>>(dist, rcov, Z, idxi, idxj, cn, n_pairs);
        pair_energy_slim<<<pgrid, 256, 0, stream>>>(dist, Z, idxi, idxj, cn, rcn, r2r4,
                                                    rc6, s6p, s8p, a1p, a2p, out, n_pairs);
    }
}